// Round 6
// baseline (2882.343 us; speedup 1.0000x reference)
//
#include <hip/hip_runtime.h>
#include <cstdint>
#include <cstddef>

#define BB 8
#define NN 8192
#define SS 2048
#define KNB 32

// Bit-exact squared distance matching numpy: (a-b) per component, squares,
// left-to-right sum, no FMA contraction.
__device__ __forceinline__ float sqdist_exact(float ax, float ay, float az,
                                              float bx, float by, float bz) {
#pragma clang fp contract(off)
    float dx = ax - bx;
    float dy = ay - by;
    float dz = az - bz;
    return (dx * dx + dy * dy) + dz * dz;
}

// DPP wave-64 reduce steps (gfx9 lineage: row_shr + row_bcast legal on CDNA4).
// old = identity, bound_ctrl=false -> invalid lanes contribute identity.
template <int CTRL>
__device__ __forceinline__ float dpp_fmax_step(float x) {
    int t = __builtin_amdgcn_update_dpp(__float_as_int(-1.0f), __float_as_int(x),
                                        CTRL, 0xf, 0xf, false);
    return fmaxf(x, __int_as_float(t));
}
template <int CTRL>
__device__ __forceinline__ int dpp_imin_step(int x) {
    int t = __builtin_amdgcn_update_dpp(0x7fffffff, x, CTRL, 0xf, 0xf, false);
    return min(x, t);
}
// u64 max reduce step via DPP (2 dpp movs + u64 cmp/select, pure VALU —
// NOT __shfl_xor, which is ds_bpermute with ~LDS latency per step).
template <int CTRL>
__device__ __forceinline__ unsigned long long dpp_u64max_step(unsigned long long k) {
    int lo = __builtin_amdgcn_update_dpp(0, (int)(unsigned)(k & 0xffffffffu),
                                         CTRL, 0xf, 0xf, false);
    int hi = __builtin_amdgcn_update_dpp(0, (int)(unsigned)(k >> 32),
                                         CTRL, 0xf, 0xf, false);
    unsigned long long o = ((unsigned long long)(unsigned)hi << 32) | (unsigned)lo;
    return (o > k) ? o : k;
}
#define ROW_SHR1 0x111
#define ROW_SHR2 0x112
#define ROW_SHR4 0x114
#define ROW_SHR8 0x118
#define ROW_BC15 0x142
#define ROW_BC31 0x143

// ---------------------------------------------------------------------------
// Weight transpose prep: w1T[c][64], w2T[j][64], w3T[j][128]
// ---------------------------------------------------------------------------
__global__ void prep_kernel(const float* __restrict__ w1, const float* __restrict__ w2,
                            const float* __restrict__ w3, float* __restrict__ w1T,
                            float* __restrict__ w2T, float* __restrict__ w3T) {
    for (int i = threadIdx.x; i < 192; i += 256) {
        int oc = i / 3, c = i % 3;
        w1T[c * 64 + oc] = w1[i];
    }
    for (int i = threadIdx.x; i < 4096; i += 256) {
        int oc = i >> 6, j = i & 63;
        w2T[j * 64 + oc] = w2[i];
    }
    for (int i = threadIdx.x; i < 8192; i += 256) {
        int oc = i >> 6, j = i & 63;
        w3T[j * 128 + oc] = w3[i];
    }
}

// spread 3-bit value to bit positions 0,3,6
__device__ __forceinline__ int part3(int v) {
    return (v & 1) | ((v & 2) << 2) | ((v & 4) << 4);
}

#define PT_LIST(X) X(0) X(1) X(2) X(3) X(4) X(5) X(6) X(7) \
                   X(8) X(9) X(10) X(11) X(12) X(13) X(14) X(15)

// ---------------------------------------------------------------------------
// FPS: one block per batch, 512 threads (8 WAVES — fewer tail replicas than
// 16; the tail is issue-bound, replicated per wave), 16 points/thread in
// macro-scalarized named registers (launch_bounds(512,2) -> 256 VGPR, no
// spill). Morton-sorted: each wave owns ~one octant -> wave-uniform exact
// bbox prune. Tail: winning wave caches candidate coords; lane0 publishes
// (key b64, coords b128); cross-wave reduce = 1 ds_read_b64 over 8 slots +
// 3 DPP row_shr u64-max steps (VALU) + readlane + ballot/ffs + 1 broadcast
// ds_read_b128. One barrier/iter (parity double-buffer).
// ---------------------------------------------------------------------------
__global__ __launch_bounds__(512, 2) void fps_kernel(const float* __restrict__ xyz_all,
                                                     float4* __restrict__ wsSorted,
                                                     float4* __restrict__ wsCtr,
                                                     float* __restrict__ out0) {
    const int b = blockIdx.x;
    const float* xyz = xyz_all + (size_t)b * NN * 3;
    float4* sorted = wsSorted + (size_t)b * NN;
    float4* ctr = wsCtr + (size_t)b * SS;
    float* o0 = out0 + (size_t)b * 3 * SS;

    __shared__ int cellCnt[512];
    __shared__ int cellBase[512];
    __shared__ unsigned long long redK[2][8];
    __shared__ float4 redC[2][8];

    const int tid = threadIdx.x;
    const int wid = tid >> 6;
    const int lane = tid & 63;

    // --- pass 1: per-Morton-cell counts (16 pts/thread)
    cellCnt[tid] = 0;
    __syncthreads();
    int cellReg[16];
#pragma unroll
    for (int j = 0; j < 16; ++j) {
        int p = tid + j * 512;
        float x = xyz[p * 3 + 0], y = xyz[p * 3 + 1], z = xyz[p * 3 + 2];
        int qx = min(7, (int)(x * 8.0f));
        int qy = min(7, (int)(y * 8.0f));
        int qz = min(7, (int)(z * 8.0f));
        cellReg[j] = part3(qx) | (part3(qy) << 1) | (part3(qz) << 2);
        atomicAdd(&cellCnt[cellReg[j]], 1);
    }
    __syncthreads();
    int myCnt = cellCnt[tid];
    // inclusive Hillis-Steele scan over 512 cells (thread==cell)
    for (int off = 1; off < 512; off <<= 1) {
        int v = (tid >= off) ? cellCnt[tid - off] : 0;
        __syncthreads();
        cellCnt[tid] += v;
        __syncthreads();
    }
    cellBase[tid] = cellCnt[tid] - myCnt;
    __syncthreads();
    // --- pass 2: scatter to global ws. Slot s stored at (s&15)*512 + (s>>4)
    // so read-back (thread t owns Morton slots 16t..16t+15) is coalesced.
#pragma unroll
    for (int j = 0; j < 16; ++j) {
        int p = tid + j * 512;
        float x = xyz[p * 3 + 0], y = xyz[p * 3 + 1], z = xyz[p * 3 + 2];
        int pos = atomicAdd(&cellBase[cellReg[j]], 1);
        sorted[(pos & 15) * 512 + (pos >> 4)] = make_float4(x, y, z, __int_as_float(p));
    }
    __threadfence();
    __syncthreads();

    // --- load own 16 Morton-contiguous points into named registers + lane bbox
    float lox = 1e30f, loy = 1e30f, loz = 1e30f;
    float hix = -1e30f, hiy = -1e30f, hiz = -1e30f;
#define DECL_PT(i)                          \
    float px##i, py##i, pz##i, dist##i;     \
    int od##i;                              \
    {                                       \
        float4 v = sorted[i * 512 + tid];   \
        px##i = v.x; py##i = v.y; pz##i = v.z; \
        od##i = __float_as_int(v.w);        \
        dist##i = 1e10f;                    \
        lox = fminf(lox, v.x); hix = fmaxf(hix, v.x); \
        loy = fminf(loy, v.y); hiy = fmaxf(hiy, v.y); \
        loz = fminf(loz, v.z); hiz = fmaxf(hiz, v.z); \
    }
    PT_LIST(DECL_PT)

    // wave bbox via one-time shfl butterfly (not on the hot path)
    float wlox = lox, wloy = loy, wloz = loz, whix = hix, whiy = hiy, whiz = hiz;
#pragma unroll
    for (int off = 1; off < 64; off <<= 1) {
        wlox = fminf(wlox, __shfl_xor(wlox, off));
        wloy = fminf(wloy, __shfl_xor(wloy, off));
        wloz = fminf(wloz, __shfl_xor(wloz, off));
        whix = fmaxf(whix, __shfl_xor(whix, off));
        whiy = fmaxf(whiy, __shfl_xor(whiy, off));
        whiz = fmaxf(whiz, __shfl_xor(whiz, off));
    }

    float cx = xyz[0], cy = xyz[1], cz = xyz[2];
    if (tid == 0) {
        o0[0] = cx; o0[SS] = cy; o0[2 * SS] = cz;
        ctr[0] = make_float4(cx, cy, cz, 0.0f);
    }

    unsigned long long waveKey =
        ((unsigned long long)__float_as_uint(1e10f) << 32) | 0xFFFFFFFFull;
    float wave_bv = 1e10f;  // max min-dist over this wave's 1024 points (cached)
    float wkx = cx, wky = cy, wkz = cz;  // cached candidate coords (wave-uniform)

    for (int s = 1; s < SS; ++s) {
        const int par = s & 1;
        // wave-uniform exact prune: if lb >= wave max dist, no dist can change
        float ddx = fmaxf(fmaxf(wlox - cx, cx - whix), 0.0f);
        float ddy = fmaxf(fmaxf(wloy - cy, cy - whiy), 0.0f);
        float ddz = fmaxf(fmaxf(wloz - cz, cz - whiz), 0.0f);
        float lb2 = ddx * ddx + ddy * ddy + ddz * ddz;
        if (lb2 * 0.999f < wave_bv) {
            float nbv = -1.0f;
#define UPD_PT(i)                                                        \
    {                                                                    \
        float d = sqdist_exact(px##i, py##i, pz##i, cx, cy, cz);         \
        dist##i = fminf(dist##i, d);                                     \
        nbv = fmaxf(nbv, dist##i);                                       \
    }
            PT_LIST(UPD_PT)
            // wave max value via DPP (VALU-speed), result in lane 63
            float m = nbv;
            m = dpp_fmax_step<ROW_SHR1>(m);
            m = dpp_fmax_step<ROW_SHR2>(m);
            m = dpp_fmax_step<ROW_SHR4>(m);
            m = dpp_fmax_step<ROW_SHR8>(m);
            m = dpp_fmax_step<ROW_BC15>(m);
            m = dpp_fmax_step<ROW_BC31>(m);
            float wv = __int_as_float(__builtin_amdgcn_readlane(__float_as_int(m), 63));
            // first-orig-index among exact max holders
            int cand = 0x7fffffff;
#define IDX_PT(i) cand = (dist##i == wv) ? min(cand, od##i) : cand;
            PT_LIST(IDX_PT)
            cand = dpp_imin_step<ROW_SHR1>(cand);
            cand = dpp_imin_step<ROW_SHR2>(cand);
            cand = dpp_imin_step<ROW_SHR4>(cand);
            cand = dpp_imin_step<ROW_SHR8>(cand);
            cand = dpp_imin_step<ROW_BC15>(cand);
            cand = dpp_imin_step<ROW_BC31>(cand);
            int wiw = __builtin_amdgcn_readlane(cand, 63);
            waveKey = ((unsigned long long)__float_as_uint(wv) << 32) |
                      (unsigned)(~(unsigned)wiw);
            wave_bv = wv;
            // broadcast candidate coords in-wave: owning lane -> readlane
            bool own = false;
            float ox = 0.f, oy = 0.f, oz = 0.f;
#define OWN_PT(i)                         \
    {                                     \
        bool m_ = (od##i == wiw);         \
        own |= m_;                        \
        ox = m_ ? px##i : ox;             \
        oy = m_ ? py##i : oy;             \
        oz = m_ ? pz##i : oz;             \
    }
            PT_LIST(OWN_PT)
            unsigned long long om = __ballot(own);
            int src = __ffsll((long long)om) - 1;
            wkx = __int_as_float(__builtin_amdgcn_readlane(__float_as_int(ox), src));
            wky = __int_as_float(__builtin_amdgcn_readlane(__float_as_int(oy), src));
            wkz = __int_as_float(__builtin_amdgcn_readlane(__float_as_int(oz), src));
        }
        if (lane == 0) {
            redK[par][wid] = waveKey;
            redC[par][wid] = make_float4(wkx, wky, wkz, 0.0f);
        }
        __syncthreads();
        // cross-wave reduce over 8 slots: 1 b64 read + 3 DPP row_shr u64-max
        // steps (lane 7 of each 16-row = max over slots 0..7), scalar
        // broadcast via readlane, slot ballot, 1 broadcast b128 coord read.
        unsigned long long ko = redK[par][lane & 7];
        unsigned long long k = ko;
        k = dpp_u64max_step<ROW_SHR1>(k);
        k = dpp_u64max_step<ROW_SHR2>(k);
        k = dpp_u64max_step<ROW_SHR4>(k);
        unsigned blo = (unsigned)__builtin_amdgcn_readlane((int)(unsigned)(k & 0xffffffffu), 7);
        unsigned bhi = (unsigned)__builtin_amdgcn_readlane((int)(unsigned)(k >> 32), 7);
        unsigned long long best = ((unsigned long long)bhi << 32) | blo;
        unsigned long long hm = __ballot((lane < 8) && (ko == best));
        int w = __ffsll((long long)hm) - 1;
        float4 c = redC[par][w];  // broadcast LDS read
        cx = c.x; cy = c.y; cz = c.z;
        if (tid == 0) {
            o0[s] = cx; o0[SS + s] = cy; o0[2 * SS + s] = cz;
            ctr[s] = make_float4(cx, cy, cz, 0.0f);
        }
    }
}

// ---------------------------------------------------------------------------
// Fused ball-query + MLP + maxpool. Block = 128 threads (2 waves), 2 centers.
// ---------------------------------------------------------------------------
__global__ __launch_bounds__(128) void bqmlp_kernel(const float* __restrict__ xyz_all,
                                                    const float4* __restrict__ wsCtr,
                                                    const float* __restrict__ w1T,
                                                    const float* __restrict__ b1,
                                                    const float* __restrict__ w2T,
                                                    const float* __restrict__ b2,
                                                    const float* __restrict__ w3T,
                                                    const float* __restrict__ b3,
                                                    float* __restrict__ out1) {
    const int b = blockIdx.x >> 10;            // 1024 blocks per batch
    const int s0 = (blockIdx.x & 1023) * 2;    // 2 centers per block
    const float* xyz = xyz_all + (size_t)b * NN * 3;

    __shared__ float relF[2 * KNB * 3];  // [64 rows][3]
    __shared__ float h1T[64 * 64];       // [ch][row]
    __shared__ float h2T[64 * 64];       // [ch][row]

    const int tid = threadIdx.x;
    const int cb = __builtin_amdgcn_readfirstlane(tid >> 6);  // wave id (uniform)
    const int l = tid & 63;

    // ---- ball query: wave cb handles center s0+cb
    {
        float4 cc = wsCtr[(size_t)b * SS + s0 + cb];
        float ccx = cc.x, ccy = cc.y, ccz = cc.z;
        const float R2 = (float)(0.2 * 0.2);
        int total = 0;
        float fx = 0.f, fy = 0.f, fz = 0.f;
        bool have = false;
        for (int chunk = 0; chunk < 128 && total < KNB; ++chunk) {
            int p = chunk * 64 + l;
            float x = xyz[p * 3 + 0], y = xyz[p * 3 + 1], z = xyz[p * 3 + 2];
            float d = sqdist_exact(ccx, ccy, ccz, x, y, z);
            bool hit = (d <= R2);
            unsigned long long mask = __ballot(hit);
            int cnt = __popcll(mask);
            if (cnt) {
                int pos = total + __popcll(mask & ((1ull << l) - 1ull));
                float rx = x - ccx, ry = y - ccy, rz = z - ccz;  // single subs: exact
                if (hit && pos < KNB) {
                    relF[(cb * KNB + pos) * 3 + 0] = rx;
                    relF[(cb * KNB + pos) * 3 + 1] = ry;
                    relF[(cb * KNB + pos) * 3 + 2] = rz;
                }
                if (hit && pos == 0) { fx = rx; fy = ry; fz = rz; have = true; }
                total += cnt;
            }
        }
        unsigned long long hm = __ballot(have);
        if (total < KNB) {
            int src = __ffsll((long long)hm) - 1;
            float gx = __shfl(fx, src), gy = __shfl(fy, src), gz = __shfl(fz, src);
            if (l >= total && l < KNB) {
                relF[(cb * KNB + l) * 3 + 0] = gx;
                relF[(cb * KNB + l) * 3 + 1] = gy;
                relF[(cb * KNB + l) * 3 + 2] = gz;
            }
        }
    }
    __syncthreads();

    const int r = l;  // row 0..63: rows 0..31 center s0, rows 32..63 center s0+1

    // ---- layer 1: rel(3) -> 64, thread covers ch block cb*32..+31 for row r
    {
        float rx = relF[r * 3 + 0], ry = relF[r * 3 + 1], rz = relF[r * 3 + 2];
#pragma unroll
        for (int i = 0; i < 32; ++i) {
            int ch = cb * 32 + i;
            float h = b1[ch];
            h = fmaf(rx, w1T[0 * 64 + ch], h);
            h = fmaf(ry, w1T[1 * 64 + ch], h);
            h = fmaf(rz, w1T[2 * 64 + ch], h);
            h1T[ch * 64 + r] = fmaxf(h, 0.0f);
        }
    }
    __syncthreads();

    // ---- layer 2: 64 -> 64
    {
        float acc[32];
#pragma unroll
        for (int i = 0; i < 32; ++i) acc[i] = b2[cb * 32 + i];
#pragma unroll 4
        for (int j = 0; j < 64; ++j) {
            float a = h1T[j * 64 + r];
            const float* wrow = w2T + j * 64 + cb * 32;
#pragma unroll
            for (int i = 0; i < 32; ++i) acc[i] = fmaf(a, wrow[i], acc[i]);
        }
#pragma unroll
        for (int i = 0; i < 32; ++i) h2T[(cb * 32 + i) * 64 + r] = fmaxf(acc[i], 0.0f);
    }
    __syncthreads();

    // ---- layer 3: 64 -> 128, fused relu + maxpool over the 32 rows/center
    {
        float acc[64];
#pragma unroll
        for (int i = 0; i < 64; ++i) acc[i] = b3[cb * 64 + i];
#pragma unroll 2
        for (int j = 0; j < 64; ++j) {
            float a = h2T[j * 64 + r];
            const float* wrow = w3T + j * 128 + cb * 64;
#pragma unroll
            for (int i = 0; i < 64; ++i) acc[i] = fmaf(a, wrow[i], acc[i]);
        }
#pragma unroll
        for (int i = 0; i < 64; ++i) {
            float v = fmaxf(acc[i], 0.0f);
            v = fmaxf(v, __shfl_xor(v, 1));
            v = fmaxf(v, __shfl_xor(v, 2));
            v = fmaxf(v, __shfl_xor(v, 4));
            v = fmaxf(v, __shfl_xor(v, 8));
            v = fmaxf(v, __shfl_xor(v, 16));
            acc[i] = v;
        }
        if ((l & 31) == 0) {
            int sA = s0 + (l >> 5);
            float* op = out1 + ((size_t)b * 128 + cb * 64) * SS + sA;
#pragma unroll
            for (int i = 0; i < 64; ++i) op[(size_t)i * SS] = acc[i];
        }
    }
}

extern "C" void kernel_launch(void* const* d_in, const int* in_sizes, int n_in,
                              void* d_out, int out_size, void* d_ws, size_t ws_size,
                              hipStream_t stream) {
    (void)in_sizes; (void)n_in; (void)out_size; (void)ws_size;
    const float* xyz = (const float*)d_in[0];
    // d_in[1] = features : unused by the reference
    const float* w1 = (const float*)d_in[2];
    const float* b1 = (const float*)d_in[3];
    const float* w2 = (const float*)d_in[4];
    const float* b2 = (const float*)d_in[5];
    const float* w3 = (const float*)d_in[6];
    const float* b3 = (const float*)d_in[7];
    float* out = (float*)d_out;

    // workspace layout
    float4* wsCtr = (float4*)d_ws;              // B*S float4      (256 KB)
    float4* wsSorted = wsCtr + BB * SS;         // B*N float4      (1 MB)
    float* w1T = (float*)(wsSorted + BB * NN);  // 192 f
    float* w2T = w1T + 192;                     // 4096 f
    float* w3T = w2T + 4096;                    // 8192 f

    prep_kernel<<<1, 256, 0, stream>>>(w1, w2, w3, w1T, w2T, w3T);
    fps_kernel<<<BB, 512, 0, stream>>>(xyz, wsSorted, wsCtr, out);
    bqmlp_kernel<<<BB * (SS / 2), 128, 0, stream>>>(xyz, wsCtr, w1T, b1, w2T, b2,
                                                    w3T, b3, out + BB * 3 * SS);
}

// Round 7
// 2575.078 us; speedup vs baseline: 1.1193x; 1.1193x over previous
//
#include <hip/hip_runtime.h>
#include <cstdint>
#include <cstddef>

#define BB 8
#define NN 8192
#define SS 2048
#define KNB 32

// Bit-exact squared distance matching numpy: (a-b) per component, squares,
// left-to-right sum, no FMA contraction.
__device__ __forceinline__ float sqdist_exact(float ax, float ay, float az,
                                              float bx, float by, float bz) {
#pragma clang fp contract(off)
    float dx = ax - bx;
    float dy = ay - by;
    float dz = az - bz;
    return (dx * dx + dy * dy) + dz * dz;
}

// DPP wave-64 reduce steps (gfx9 lineage: row_shr + row_bcast legal on CDNA4).
// old = identity, bound_ctrl=false -> invalid lanes contribute identity.
template <int CTRL>
__device__ __forceinline__ float dpp_fmax_step(float x) {
    int t = __builtin_amdgcn_update_dpp(__float_as_int(-1.0f), __float_as_int(x),
                                        CTRL, 0xf, 0xf, false);
    return fmaxf(x, __int_as_float(t));
}
template <int CTRL>
__device__ __forceinline__ int dpp_imin_step(int x) {
    int t = __builtin_amdgcn_update_dpp(0x7fffffff, x, CTRL, 0xf, 0xf, false);
    return min(x, t);
}
// u64 max reduce step via DPP (2 dpp movs + u64 cmp/select, pure VALU —
// NOT __shfl_xor, which is ds_bpermute with ~LDS latency per step).
template <int CTRL>
__device__ __forceinline__ unsigned long long dpp_u64max_step(unsigned long long k) {
    int lo = __builtin_amdgcn_update_dpp(0, (int)(unsigned)(k & 0xffffffffu),
                                         CTRL, 0xf, 0xf, false);
    int hi = __builtin_amdgcn_update_dpp(0, (int)(unsigned)(k >> 32),
                                         CTRL, 0xf, 0xf, false);
    unsigned long long o = ((unsigned long long)(unsigned)hi << 32) | (unsigned)lo;
    return (o > k) ? o : k;
}
#define ROW_SHR1 0x111
#define ROW_SHR2 0x112
#define ROW_SHR4 0x114
#define ROW_SHR8 0x118
#define ROW_BC15 0x142
#define ROW_BC31 0x143

// ---------------------------------------------------------------------------
// Weight transpose prep: w1T[c][64], w2T[j][64], w3T[j][128]
// ---------------------------------------------------------------------------
__global__ void prep_kernel(const float* __restrict__ w1, const float* __restrict__ w2,
                            const float* __restrict__ w3, float* __restrict__ w1T,
                            float* __restrict__ w2T, float* __restrict__ w3T) {
    for (int i = threadIdx.x; i < 192; i += 256) {
        int oc = i / 3, c = i % 3;
        w1T[c * 64 + oc] = w1[i];
    }
    for (int i = threadIdx.x; i < 4096; i += 256) {
        int oc = i >> 6, j = i & 63;
        w2T[j * 64 + oc] = w2[i];
    }
    for (int i = threadIdx.x; i < 8192; i += 256) {
        int oc = i >> 6, j = i & 63;
        w3T[j * 128 + oc] = w3[i];
    }
}

// spread 3-bit value to bit positions 0,3,6
__device__ __forceinline__ int part3(int v) {
    return (v & 1) | ((v & 2) << 2) | ((v & 4) << 4);
}

#define PT_LIST(X) X(0) X(1) X(2) X(3) X(4) X(5) X(6) X(7)

// ---------------------------------------------------------------------------
// FPS: one block per batch, 1024 threads (16 waves), 8 points/thread in named
// registers (the ONLY verified no-spill config: 16 pts/thread spills at
// VGPR=72 regardless of launch_bounds — R1/R5 evidence). Morton-sorted ->
// wave-uniform exact bbox prune. NO GLOBAL MEMORY OPS IN THE LOOP: centers
// banked in per-thread registers (thread s&1023, slot s>>10), o0/ctr written
// coalesced after the loop -> __syncthreads needs only lgkmcnt drain, not a
// vmcnt(0) HBM-store drain every iteration. Tail: lane0 publishes key (b64),
// candidate-owning lane publishes coords (b128, ownership cached across
// pruned iters); after barrier each lane reads key+coords back-to-back
// (latency overlapped), 4 DPP row_shr u64-max steps, readlane, slot ballot,
// coords via 3 readlanes of the already-loaded b128 (no dependent LDS read).
// ---------------------------------------------------------------------------
__global__ __launch_bounds__(1024, 4) void fps_kernel(const float* __restrict__ xyz_all,
                                                      float4* __restrict__ wsSorted,
                                                      float4* __restrict__ wsCtr,
                                                      float* __restrict__ out0) {
    const int b = blockIdx.x;
    const float* xyz = xyz_all + (size_t)b * NN * 3;
    float4* sorted = wsSorted + (size_t)b * NN;
    float4* ctr = wsCtr + (size_t)b * SS;
    float* o0 = out0 + (size_t)b * 3 * SS;

    __shared__ int cellCnt[512];
    __shared__ int cellBase[512];
    __shared__ unsigned long long redK[2][16];
    __shared__ float4 redC[2][16];

    const int tid = threadIdx.x;
    const int wid = tid >> 6;
    const int lane = tid & 63;

    // --- pass 1: per-Morton-cell counts (8 pts/thread)
    if (tid < 512) cellCnt[tid] = 0;
    __syncthreads();
    int cellReg[8];
#pragma unroll
    for (int j = 0; j < 8; ++j) {
        int p = tid + j * 1024;
        float x = xyz[p * 3 + 0], y = xyz[p * 3 + 1], z = xyz[p * 3 + 2];
        int qx = min(7, (int)(x * 8.0f));
        int qy = min(7, (int)(y * 8.0f));
        int qz = min(7, (int)(z * 8.0f));
        cellReg[j] = part3(qx) | (part3(qy) << 1) | (part3(qz) << 2);
        atomicAdd(&cellCnt[cellReg[j]], 1);
    }
    __syncthreads();
    int myCnt = (tid < 512) ? cellCnt[tid] : 0;
    // inclusive Hillis-Steele scan over 512 cells (thread==cell), barriers uniform
    for (int off = 1; off < 512; off <<= 1) {
        int v = 0;
        if (tid < 512 && tid >= off) v = cellCnt[tid - off];
        __syncthreads();
        if (tid < 512) cellCnt[tid] += v;
        __syncthreads();
    }
    if (tid < 512) cellBase[tid] = cellCnt[tid] - myCnt;
    __syncthreads();
    // --- pass 2: scatter to global ws. Slot s stored at (s&7)*1024 + (s>>3)
    // so read-back (thread t owns Morton slots 8t..8t+7) is coalesced.
#pragma unroll
    for (int j = 0; j < 8; ++j) {
        int p = tid + j * 1024;
        float x = xyz[p * 3 + 0], y = xyz[p * 3 + 1], z = xyz[p * 3 + 2];
        int pos = atomicAdd(&cellBase[cellReg[j]], 1);
        sorted[(pos & 7) * 1024 + (pos >> 3)] = make_float4(x, y, z, __int_as_float(p));
    }
    __threadfence();
    __syncthreads();

    // --- load own 8 Morton-contiguous points into named registers + lane bbox
    float lox = 1e30f, loy = 1e30f, loz = 1e30f;
    float hix = -1e30f, hiy = -1e30f, hiz = -1e30f;
#define DECL_PT(i)                          \
    float px##i, py##i, pz##i, dist##i;     \
    int od##i;                              \
    {                                       \
        float4 v = sorted[i * 1024 + tid];  \
        px##i = v.x; py##i = v.y; pz##i = v.z; \
        od##i = __float_as_int(v.w);        \
        dist##i = 1e10f;                    \
        lox = fminf(lox, v.x); hix = fmaxf(hix, v.x); \
        loy = fminf(loy, v.y); hiy = fmaxf(hiy, v.y); \
        loz = fminf(loz, v.z); hiz = fmaxf(hiz, v.z); \
    }
    PT_LIST(DECL_PT)

    // wave bbox via one-time shfl butterfly (not on the hot path)
    float wlox = lox, wloy = loy, wloz = loz, whix = hix, whiy = hiy, whiz = hiz;
#pragma unroll
    for (int off = 1; off < 64; off <<= 1) {
        wlox = fminf(wlox, __shfl_xor(wlox, off));
        wloy = fminf(wloy, __shfl_xor(wloy, off));
        wloz = fminf(wloz, __shfl_xor(wloz, off));
        whix = fmaxf(whix, __shfl_xor(whix, off));
        whiy = fmaxf(whiy, __shfl_xor(whiy, off));
        whiz = fmaxf(whiz, __shfl_xor(whiz, off));
    }

    float cx = xyz[0], cy = xyz[1], cz = xyz[2];
    const float ix = cx, iy = cy, iz = cz;  // s=0 center, written at the end

    unsigned long long waveKey =
        ((unsigned long long)__float_as_uint(1e10f) << 32) | 0xFFFFFFFFull;
    float wave_bv = 1e10f;  // max min-dist over this wave's 512 points (cached)
    bool own = false;       // this lane owns the wave's cached candidate point
    float okx = cx, oky = cy, okz = cz;  // owner-lane cached candidate coords

    float b0x = 0.f, b0y = 0.f, b0z = 0.f;  // banked center, s = tid (tid>=1)
    float b1x = 0.f, b1y = 0.f, b1z = 0.f;  // banked center, s = tid + 1024

    for (int s = 1; s < SS; ++s) {
        const int par = s & 1;
        // wave-uniform exact prune: if lb >= wave max dist, no dist can change
        float ddx = fmaxf(fmaxf(wlox - cx, cx - whix), 0.0f);
        float ddy = fmaxf(fmaxf(wloy - cy, cy - whiy), 0.0f);
        float ddz = fmaxf(fmaxf(wloz - cz, cz - whiz), 0.0f);
        float lb2 = ddx * ddx + ddy * ddy + ddz * ddz;
        if (lb2 * 0.999f < wave_bv) {
            float nbv = -1.0f;
#define UPD_PT(i)                                                        \
    {                                                                    \
        float d = sqdist_exact(px##i, py##i, pz##i, cx, cy, cz);         \
        dist##i = fminf(dist##i, d);                                     \
        nbv = fmaxf(nbv, dist##i);                                       \
    }
            PT_LIST(UPD_PT)
            // wave max value via DPP (VALU-speed), result in lane 63
            float m = nbv;
            m = dpp_fmax_step<ROW_SHR1>(m);
            m = dpp_fmax_step<ROW_SHR2>(m);
            m = dpp_fmax_step<ROW_SHR4>(m);
            m = dpp_fmax_step<ROW_SHR8>(m);
            m = dpp_fmax_step<ROW_BC15>(m);
            m = dpp_fmax_step<ROW_BC31>(m);
            float wv = __int_as_float(__builtin_amdgcn_readlane(__float_as_int(m), 63));
            // first-orig-index among exact max holders
            int cand = 0x7fffffff;
#define IDX_PT(i) cand = (dist##i == wv) ? min(cand, od##i) : cand;
            PT_LIST(IDX_PT)
            cand = dpp_imin_step<ROW_SHR1>(cand);
            cand = dpp_imin_step<ROW_SHR2>(cand);
            cand = dpp_imin_step<ROW_SHR4>(cand);
            cand = dpp_imin_step<ROW_SHR8>(cand);
            cand = dpp_imin_step<ROW_BC15>(cand);
            cand = dpp_imin_step<ROW_BC31>(cand);
            int wiw = __builtin_amdgcn_readlane(cand, 63);
            waveKey = ((unsigned long long)__float_as_uint(wv) << 32) |
                      (unsigned)(~(unsigned)wiw);
            wave_bv = wv;
            // candidate ownership: exactly one lane holds point wiw
            own = false;
#define OWN_PT(i)                         \
    {                                     \
        bool m_ = (od##i == wiw);         \
        own |= m_;                        \
        okx = m_ ? px##i : okx;           \
        oky = m_ ? py##i : oky;           \
        okz = m_ ? pz##i : okz;           \
    }
            PT_LIST(OWN_PT)
        }
        // publish (pruned waves republish cached values; parity double-buffer)
        if (lane == 0) redK[par][wid] = waveKey;
        if (own) redC[par][wid] = make_float4(okx, oky, okz, 0.0f);
        __syncthreads();  // lgkmcnt-only drain: no global ops in the loop
        // cross-wave reduce: key+coords read back-to-back (overlapped), then
        // 4 DPP row_shr u64-max steps (lane 15 of each row = max of 16 slots)
        unsigned long long ko = redK[par][lane & 15];
        float4 co = redC[par][lane & 15];
        unsigned long long k = ko;
        k = dpp_u64max_step<ROW_SHR1>(k);
        k = dpp_u64max_step<ROW_SHR2>(k);
        k = dpp_u64max_step<ROW_SHR4>(k);
        k = dpp_u64max_step<ROW_SHR8>(k);
        unsigned blo = (unsigned)__builtin_amdgcn_readlane((int)(unsigned)(k & 0xffffffffu), 15);
        unsigned bhi = (unsigned)__builtin_amdgcn_readlane((int)(unsigned)(k >> 32), 15);
        unsigned long long best = ((unsigned long long)bhi << 32) | blo;
        unsigned long long hm = __ballot((lane < 16) && (ko == best));
        int w = __ffsll((long long)hm) - 1;
        cx = __int_as_float(__builtin_amdgcn_readlane(__float_as_int(co.x), w));
        cy = __int_as_float(__builtin_amdgcn_readlane(__float_as_int(co.y), w));
        cz = __int_as_float(__builtin_amdgcn_readlane(__float_as_int(co.z), w));
        // bank the selected center in registers (no global store in loop)
        if (tid == (s & 1023)) {
            if (s < 1024) { b0x = cx; b0y = cy; b0z = cz; }
            else          { b1x = cx; b1y = cy; b1z = cz; }
        }
    }

    // --- write out banked centers, coalesced
    if (tid == 0) {
        o0[0] = ix; o0[SS] = iy; o0[2 * SS] = iz;
        ctr[0] = make_float4(ix, iy, iz, 0.0f);
    } else {
        o0[tid] = b0x; o0[SS + tid] = b0y; o0[2 * SS + tid] = b0z;
        ctr[tid] = make_float4(b0x, b0y, b0z, 0.0f);
    }
    {
        int s2 = tid + 1024;
        o0[s2] = b1x; o0[SS + s2] = b1y; o0[2 * SS + s2] = b1z;
        ctr[s2] = make_float4(b1x, b1y, b1z, 0.0f);
    }
}

// ---------------------------------------------------------------------------
// Fused ball-query + MLP + maxpool. Block = 128 threads (2 waves), 2 centers.
// ---------------------------------------------------------------------------
__global__ __launch_bounds__(128) void bqmlp_kernel(const float* __restrict__ xyz_all,
                                                    const float4* __restrict__ wsCtr,
                                                    const float* __restrict__ w1T,
                                                    const float* __restrict__ b1,
                                                    const float* __restrict__ w2T,
                                                    const float* __restrict__ b2,
                                                    const float* __restrict__ w3T,
                                                    const float* __restrict__ b3,
                                                    float* __restrict__ out1) {
    const int b = blockIdx.x >> 10;            // 1024 blocks per batch
    const int s0 = (blockIdx.x & 1023) * 2;    // 2 centers per block
    const float* xyz = xyz_all + (size_t)b * NN * 3;

    __shared__ float relF[2 * KNB * 3];  // [64 rows][3]
    __shared__ float h1T[64 * 64];       // [ch][row]
    __shared__ float h2T[64 * 64];       // [ch][row]

    const int tid = threadIdx.x;
    const int cb = __builtin_amdgcn_readfirstlane(tid >> 6);  // wave id (uniform)
    const int l = tid & 63;

    // ---- ball query: wave cb handles center s0+cb
    {
        float4 cc = wsCtr[(size_t)b * SS + s0 + cb];
        float ccx = cc.x, ccy = cc.y, ccz = cc.z;
        const float R2 = (float)(0.2 * 0.2);
        int total = 0;
        float fx = 0.f, fy = 0.f, fz = 0.f;
        bool have = false;
        for (int chunk = 0; chunk < 128 && total < KNB; ++chunk) {
            int p = chunk * 64 + l;
            float x = xyz[p * 3 + 0], y = xyz[p * 3 + 1], z = xyz[p * 3 + 2];
            float d = sqdist_exact(ccx, ccy, ccz, x, y, z);
            bool hit = (d <= R2);
            unsigned long long mask = __ballot(hit);
            int cnt = __popcll(mask);
            if (cnt) {
                int pos = total + __popcll(mask & ((1ull << l) - 1ull));
                float rx = x - ccx, ry = y - ccy, rz = z - ccz;  // single subs: exact
                if (hit && pos < KNB) {
                    relF[(cb * KNB + pos) * 3 + 0] = rx;
                    relF[(cb * KNB + pos) * 3 + 1] = ry;
                    relF[(cb * KNB + pos) * 3 + 2] = rz;
                }
                if (hit && pos == 0) { fx = rx; fy = ry; fz = rz; have = true; }
                total += cnt;
            }
        }
        unsigned long long hm = __ballot(have);
        if (total < KNB) {
            int src = __ffsll((long long)hm) - 1;
            float gx = __shfl(fx, src), gy = __shfl(fy, src), gz = __shfl(fz, src);
            if (l >= total && l < KNB) {
                relF[(cb * KNB + l) * 3 + 0] = gx;
                relF[(cb * KNB + l) * 3 + 1] = gy;
                relF[(cb * KNB + l) * 3 + 2] = gz;
            }
        }
    }
    __syncthreads();

    const int r = l;  // row 0..63: rows 0..31 center s0, rows 32..63 center s0+1

    // ---- layer 1: rel(3) -> 64, thread covers ch block cb*32..+31 for row r
    {
        float rx = relF[r * 3 + 0], ry = relF[r * 3 + 1], rz = relF[r * 3 + 2];
#pragma unroll
        for (int i = 0; i < 32; ++i) {
            int ch = cb * 32 + i;
            float h = b1[ch];
            h = fmaf(rx, w1T[0 * 64 + ch], h);
            h = fmaf(ry, w1T[1 * 64 + ch], h);
            h = fmaf(rz, w1T[2 * 64 + ch], h);
            h1T[ch * 64 + r] = fmaxf(h, 0.0f);
        }
    }
    __syncthreads();

    // ---- layer 2: 64 -> 64
    {
        float acc[32];
#pragma unroll
        for (int i = 0; i < 32; ++i) acc[i] = b2[cb * 32 + i];
#pragma unroll 4
        for (int j = 0; j < 64; ++j) {
            float a = h1T[j * 64 + r];
            const float* wrow = w2T + j * 64 + cb * 32;
#pragma unroll
            for (int i = 0; i < 32; ++i) acc[i] = fmaf(a, wrow[i], acc[i]);
        }
#pragma unroll
        for (int i = 0; i < 32; ++i) h2T[(cb * 32 + i) * 64 + r] = fmaxf(acc[i], 0.0f);
    }
    __syncthreads();

    // ---- layer 3: 64 -> 128, fused relu + maxpool over the 32 rows/center
    {
        float acc[64];
#pragma unroll
        for (int i = 0; i < 64; ++i) acc[i] = b3[cb * 64 + i];
#pragma unroll 2
        for (int j = 0; j < 64; ++j) {
            float a = h2T[j * 64 + r];
            const float* wrow = w3T + j * 128 + cb * 64;
#pragma unroll
            for (int i = 0; i < 64; ++i) acc[i] = fmaf(a, wrow[i], acc[i]);
        }
#pragma unroll
        for (int i = 0; i < 64; ++i) {
            float v = fmaxf(acc[i], 0.0f);
            v = fmaxf(v, __shfl_xor(v, 1));
            v = fmaxf(v, __shfl_xor(v, 2));
            v = fmaxf(v, __shfl_xor(v, 4));
            v = fmaxf(v, __shfl_xor(v, 8));
            v = fmaxf(v, __shfl_xor(v, 16));
            acc[i] = v;
        }
        if ((l & 31) == 0) {
            int sA = s0 + (l >> 5);
            float* op = out1 + ((size_t)b * 128 + cb * 64) * SS + sA;
#pragma unroll
            for (int i = 0; i < 64; ++i) op[(size_t)i * SS] = acc[i];
        }
    }
}

extern "C" void kernel_launch(void* const* d_in, const int* in_sizes, int n_in,
                              void* d_out, int out_size, void* d_ws, size_t ws_size,
                              hipStream_t stream) {
    (void)in_sizes; (void)n_in; (void)out_size; (void)ws_size;
    const float* xyz = (const float*)d_in[0];
    // d_in[1] = features : unused by the reference
    const float* w1 = (const float*)d_in[2];
    const float* b1 = (const float*)d_in[3];
    const float* w2 = (const float*)d_in[4];
    const float* b2 = (const float*)d_in[5];
    const float* w3 = (const float*)d_in[6];
    const float* b3 = (const float*)d_in[7];
    float* out = (float*)d_out;

    // workspace layout
    float4* wsCtr = (float4*)d_ws;              // B*S float4      (256 KB)
    float4* wsSorted = wsCtr + BB * SS;         // B*N float4      (1 MB)
    float* w1T = (float*)(wsSorted + BB * NN);  // 192 f
    float* w2T = w1T + 192;                     // 4096 f
    float* w3T = w2T + 4096;                    // 8192 f

    prep_kernel<<<1, 256, 0, stream>>>(w1, w2, w3, w1T, w2T, w3T);
    fps_kernel<<<BB, 1024, 0, stream>>>(xyz, wsSorted, wsCtr, out);
    bqmlp_kernel<<<BB * (SS / 2), 128, 0, stream>>>(xyz, wsCtr, w1T, b1, w2T, b2,
                                                    w3T, b3, out + BB * 3 * SS);
}

// Round 8
// 2279.744 us; speedup vs baseline: 1.2643x; 1.1295x over previous
//
#include <hip/hip_runtime.h>
#include <cstdint>
#include <cstddef>

#define BB 8
#define NN 8192
#define SS 2048
#define KNB 32

// Bit-exact squared distance matching numpy: (a-b) per component, squares,
// left-to-right sum, no FMA contraction.
__device__ __forceinline__ float sqdist_exact(float ax, float ay, float az,
                                              float bx, float by, float bz) {
#pragma clang fp contract(off)
    float dx = ax - bx;
    float dy = ay - by;
    float dz = az - bz;
    return (dx * dx + dy * dy) + dz * dz;
}

// DPP wave-64 reduce steps (gfx9 lineage: row_shr + row_bcast legal on CDNA4).
// old = identity, bound_ctrl=false -> invalid lanes contribute identity.
template <int CTRL>
__device__ __forceinline__ float dpp_fmax_step(float x) {
    int t = __builtin_amdgcn_update_dpp(__float_as_int(-1.0f), __float_as_int(x),
                                        CTRL, 0xf, 0xf, false);
    return fmaxf(x, __int_as_float(t));
}
template <int CTRL>
__device__ __forceinline__ int dpp_imin_step(int x) {
    int t = __builtin_amdgcn_update_dpp(0x7fffffff, x, CTRL, 0xf, 0xf, false);
    return min(x, t);
}
#define ROW_SHR1 0x111
#define ROW_SHR2 0x112
#define ROW_SHR4 0x114
#define ROW_SHR8 0x118
#define ROW_BC15 0x142
#define ROW_BC31 0x143

// ---------------------------------------------------------------------------
// Weight transpose prep: w1T[c][64], w2T[j][64], w3T[j][128]
// ---------------------------------------------------------------------------
__global__ void prep_kernel(const float* __restrict__ w1, const float* __restrict__ w2,
                            const float* __restrict__ w3, float* __restrict__ w1T,
                            float* __restrict__ w2T, float* __restrict__ w3T) {
    for (int i = threadIdx.x; i < 192; i += 256) {
        int oc = i / 3, c = i % 3;
        w1T[c * 64 + oc] = w1[i];
    }
    for (int i = threadIdx.x; i < 4096; i += 256) {
        int oc = i >> 6, j = i & 63;
        w2T[j * 64 + oc] = w2[i];
    }
    for (int i = threadIdx.x; i < 8192; i += 256) {
        int oc = i >> 6, j = i & 63;
        w3T[j * 128 + oc] = w3[i];
    }
}

// spread 3-bit value to bit positions 0,3,6
__device__ __forceinline__ int part3(int v) {
    return (v & 1) | ((v & 2) << 2) | ((v & 4) << 4);
}

#define PT_LIST(X) X(0) X(1) X(2) X(3) X(4) X(5) X(6) X(7) \
                   X(8) X(9) X(10) X(11) X(12) X(13) X(14) X(15)

// ---------------------------------------------------------------------------
// FPS: one block per batch, 512 threads (8 waves — HALF the tail replicas and
// barrier cohort of the 1024-thread variant), 16 points/thread in named
// registers. amdgpu_waves_per_eu(2,2) FORCES the 256-VGPR budget (plain
// __launch_bounds__ min-waves is only a hint — R1/R5 showed the allocator
// targets 7 waves/EU and spills at VGPR=72). Structure otherwise identical to
// the empirically-best 1938-us kernel: Morton sort -> wave-uniform exact bbox
// prune; DPP argmax in-wave; lane0 publishes key; ALL waves read the 8 slots
// with a compare chain; winner coords via readfirstlane + s_load broadcast;
// one barrier/iter (parity double-buffer).
// ---------------------------------------------------------------------------
__global__ __attribute__((amdgpu_flat_work_group_size(512, 512),
                          amdgpu_waves_per_eu(2, 2)))
void fps_kernel(const float* __restrict__ xyz_all,
                float4* __restrict__ wsSorted,
                float4* __restrict__ wsCtr,
                float* __restrict__ out0) {
    const int b = blockIdx.x;
    const float* xyz = xyz_all + (size_t)b * NN * 3;
    float4* sorted = wsSorted + (size_t)b * NN;
    float4* ctr = wsCtr + (size_t)b * SS;
    float* o0 = out0 + (size_t)b * 3 * SS;

    __shared__ int cellCnt[512];
    __shared__ int cellBase[512];
    __shared__ unsigned long long red[2][8];

    const int tid = threadIdx.x;
    const int wid = tid >> 6;
    const int lane = tid & 63;

    // --- pass 1: per-Morton-cell counts (16 pts/thread)
    cellCnt[tid] = 0;
    __syncthreads();
    int cellReg[16];
#pragma unroll
    for (int j = 0; j < 16; ++j) {
        int p = tid + j * 512;
        float x = xyz[p * 3 + 0], y = xyz[p * 3 + 1], z = xyz[p * 3 + 2];
        int qx = min(7, (int)(x * 8.0f));
        int qy = min(7, (int)(y * 8.0f));
        int qz = min(7, (int)(z * 8.0f));
        cellReg[j] = part3(qx) | (part3(qy) << 1) | (part3(qz) << 2);
        atomicAdd(&cellCnt[cellReg[j]], 1);
    }
    __syncthreads();
    int myCnt = cellCnt[tid];
    // inclusive Hillis-Steele scan over 512 cells (thread==cell)
    for (int off = 1; off < 512; off <<= 1) {
        int v = (tid >= off) ? cellCnt[tid - off] : 0;
        __syncthreads();
        cellCnt[tid] += v;
        __syncthreads();
    }
    cellBase[tid] = cellCnt[tid] - myCnt;
    __syncthreads();
    // --- pass 2: scatter to global ws. Slot s stored at (s&15)*512 + (s>>4)
    // so read-back (thread t owns Morton slots 16t..16t+15) is coalesced.
#pragma unroll
    for (int j = 0; j < 16; ++j) {
        int p = tid + j * 512;
        float x = xyz[p * 3 + 0], y = xyz[p * 3 + 1], z = xyz[p * 3 + 2];
        int pos = atomicAdd(&cellBase[cellReg[j]], 1);
        sorted[(pos & 15) * 512 + (pos >> 4)] = make_float4(x, y, z, __int_as_float(p));
    }
    __threadfence();
    __syncthreads();

    // --- load own 16 Morton-contiguous points into named registers + lane bbox
    float lox = 1e30f, loy = 1e30f, loz = 1e30f;
    float hix = -1e30f, hiy = -1e30f, hiz = -1e30f;
#define DECL_PT(i)                          \
    float px##i, py##i, pz##i, dist##i;     \
    int od##i;                              \
    {                                       \
        float4 v = sorted[i * 512 + tid];   \
        px##i = v.x; py##i = v.y; pz##i = v.z; \
        od##i = __float_as_int(v.w);        \
        dist##i = 1e10f;                    \
        lox = fminf(lox, v.x); hix = fmaxf(hix, v.x); \
        loy = fminf(loy, v.y); hiy = fmaxf(hiy, v.y); \
        loz = fminf(loz, v.z); hiz = fmaxf(hiz, v.z); \
    }
    PT_LIST(DECL_PT)

    // wave bbox via one-time shfl butterfly (not on the hot path)
    float wlox = lox, wloy = loy, wloz = loz, whix = hix, whiy = hiy, whiz = hiz;
#pragma unroll
    for (int off = 1; off < 64; off <<= 1) {
        wlox = fminf(wlox, __shfl_xor(wlox, off));
        wloy = fminf(wloy, __shfl_xor(wloy, off));
        wloz = fminf(wloz, __shfl_xor(wloz, off));
        whix = fmaxf(whix, __shfl_xor(whix, off));
        whiy = fmaxf(whiy, __shfl_xor(whiy, off));
        whiz = fmaxf(whiz, __shfl_xor(whiz, off));
    }

    float cx = xyz[0], cy = xyz[1], cz = xyz[2];
    if (tid == 0) {
        o0[0] = cx; o0[SS] = cy; o0[2 * SS] = cz;
        ctr[0] = make_float4(cx, cy, cz, 0.0f);
    }

    unsigned long long waveKey =
        ((unsigned long long)__float_as_uint(1e10f) << 32) | 0xFFFFFFFFull;
    float wave_bv = 1e10f;  // max min-dist over this wave's 1024 points (cached)

    for (int s = 1; s < SS; ++s) {
        const int par = s & 1;
        // wave-uniform exact prune: if lb >= wave max dist, no dist can change
        float ddx = fmaxf(fmaxf(wlox - cx, cx - whix), 0.0f);
        float ddy = fmaxf(fmaxf(wloy - cy, cy - whiy), 0.0f);
        float ddz = fmaxf(fmaxf(wloz - cz, cz - whiz), 0.0f);
        float lb2 = ddx * ddx + ddy * ddy + ddz * ddz;
        if (lb2 * 0.999f < wave_bv) {
            float nbv = -1.0f;
#define UPD_PT(i)                                                        \
    {                                                                    \
        float d = sqdist_exact(px##i, py##i, pz##i, cx, cy, cz);         \
        dist##i = fminf(dist##i, d);                                     \
        nbv = fmaxf(nbv, dist##i);                                       \
    }
            PT_LIST(UPD_PT)
            // wave max value via DPP (VALU-speed), result in lane 63
            float m = nbv;
            m = dpp_fmax_step<ROW_SHR1>(m);
            m = dpp_fmax_step<ROW_SHR2>(m);
            m = dpp_fmax_step<ROW_SHR4>(m);
            m = dpp_fmax_step<ROW_SHR8>(m);
            m = dpp_fmax_step<ROW_BC15>(m);
            m = dpp_fmax_step<ROW_BC31>(m);
            float wv = __int_as_float(__builtin_amdgcn_readlane(__float_as_int(m), 63));
            // first-orig-index among exact max holders
            int cand = 0x7fffffff;
#define IDX_PT(i) cand = (dist##i == wv) ? min(cand, od##i) : cand;
            PT_LIST(IDX_PT)
            cand = dpp_imin_step<ROW_SHR1>(cand);
            cand = dpp_imin_step<ROW_SHR2>(cand);
            cand = dpp_imin_step<ROW_SHR4>(cand);
            cand = dpp_imin_step<ROW_SHR8>(cand);
            cand = dpp_imin_step<ROW_BC15>(cand);
            cand = dpp_imin_step<ROW_BC31>(cand);
            int wiw = __builtin_amdgcn_readlane(cand, 63);
            waveKey = ((unsigned long long)__float_as_uint(wv) << 32) |
                      (unsigned)(~(unsigned)wiw);
            wave_bv = wv;
        }
        if (lane == 0) red[par][wid] = waveKey;
        __syncthreads();
        unsigned long long best = red[par][0];
#pragma unroll
        for (int k = 1; k < 8; ++k) {
            unsigned long long o = red[par][k];
            best = (o > best) ? o : best;
        }
        int wi = (int)(~(unsigned)best);
        int wiu = __builtin_amdgcn_readfirstlane(wi);
        cx = xyz[wiu * 3 + 0];  // scalar broadcast load (s_load)
        cy = xyz[wiu * 3 + 1];
        cz = xyz[wiu * 3 + 2];
        if (tid == 0) {
            o0[s] = cx; o0[SS + s] = cy; o0[2 * SS + s] = cz;
            ctr[s] = make_float4(cx, cy, cz, 0.0f);
        }
    }
}

// ---------------------------------------------------------------------------
// Fused ball-query + MLP + maxpool. Block = 128 threads (2 waves), 2 centers.
// ---------------------------------------------------------------------------
__global__ __launch_bounds__(128) void bqmlp_kernel(const float* __restrict__ xyz_all,
                                                    const float4* __restrict__ wsCtr,
                                                    const float* __restrict__ w1T,
                                                    const float* __restrict__ b1,
                                                    const float* __restrict__ w2T,
                                                    const float* __restrict__ b2,
                                                    const float* __restrict__ w3T,
                                                    const float* __restrict__ b3,
                                                    float* __restrict__ out1) {
    const int b = blockIdx.x >> 10;            // 1024 blocks per batch
    const int s0 = (blockIdx.x & 1023) * 2;    // 2 centers per block
    const float* xyz = xyz_all + (size_t)b * NN * 3;

    __shared__ float relF[2 * KNB * 3];  // [64 rows][3]
    __shared__ float h1T[64 * 64];       // [ch][row]
    __shared__ float h2T[64 * 64];       // [ch][row]

    const int tid = threadIdx.x;
    const int cb = __builtin_amdgcn_readfirstlane(tid >> 6);  // wave id (uniform)
    const int l = tid & 63;

    // ---- ball query: wave cb handles center s0+cb
    {
        float4 cc = wsCtr[(size_t)b * SS + s0 + cb];
        float ccx = cc.x, ccy = cc.y, ccz = cc.z;
        const float R2 = (float)(0.2 * 0.2);
        int total = 0;
        float fx = 0.f, fy = 0.f, fz = 0.f;
        bool have = false;
        for (int chunk = 0; chunk < 128 && total < KNB; ++chunk) {
            int p = chunk * 64 + l;
            float x = xyz[p * 3 + 0], y = xyz[p * 3 + 1], z = xyz[p * 3 + 2];
            float d = sqdist_exact(ccx, ccy, ccz, x, y, z);
            bool hit = (d <= R2);
            unsigned long long mask = __ballot(hit);
            int cnt = __popcll(mask);
            if (cnt) {
                int pos = total + __popcll(mask & ((1ull << l) - 1ull));
                float rx = x - ccx, ry = y - ccy, rz = z - ccz;  // single subs: exact
                if (hit && pos < KNB) {
                    relF[(cb * KNB + pos) * 3 + 0] = rx;
                    relF[(cb * KNB + pos) * 3 + 1] = ry;
                    relF[(cb * KNB + pos) * 3 + 2] = rz;
                }
                if (hit && pos == 0) { fx = rx; fy = ry; fz = rz; have = true; }
                total += cnt;
            }
        }
        unsigned long long hm = __ballot(have);
        if (total < KNB) {
            int src = __ffsll((long long)hm) - 1;
            float gx = __shfl(fx, src), gy = __shfl(fy, src), gz = __shfl(fz, src);
            if (l >= total && l < KNB) {
                relF[(cb * KNB + l) * 3 + 0] = gx;
                relF[(cb * KNB + l) * 3 + 1] = gy;
                relF[(cb * KNB + l) * 3 + 2] = gz;
            }
        }
    }
    __syncthreads();

    const int r = l;  // row 0..63: rows 0..31 center s0, rows 32..63 center s0+1

    // ---- layer 1: rel(3) -> 64, thread covers ch block cb*32..+31 for row r
    {
        float rx = relF[r * 3 + 0], ry = relF[r * 3 + 1], rz = relF[r * 3 + 2];
#pragma unroll
        for (int i = 0; i < 32; ++i) {
            int ch = cb * 32 + i;
            float h = b1[ch];
            h = fmaf(rx, w1T[0 * 64 + ch], h);
            h = fmaf(ry, w1T[1 * 64 + ch], h);
            h = fmaf(rz, w1T[2 * 64 + ch], h);
            h1T[ch * 64 + r] = fmaxf(h, 0.0f);
        }
    }
    __syncthreads();

    // ---- layer 2: 64 -> 64
    {
        float acc[32];
#pragma unroll
        for (int i = 0; i < 32; ++i) acc[i] = b2[cb * 32 + i];
#pragma unroll 4
        for (int j = 0; j < 64; ++j) {
            float a = h1T[j * 64 + r];
            const float* wrow = w2T + j * 64 + cb * 32;
#pragma unroll
            for (int i = 0; i < 32; ++i) acc[i] = fmaf(a, wrow[i], acc[i]);
        }
#pragma unroll
        for (int i = 0; i < 32; ++i) h2T[(cb * 32 + i) * 64 + r] = fmaxf(acc[i], 0.0f);
    }
    __syncthreads();

    // ---- layer 3: 64 -> 128, fused relu + maxpool over the 32 rows/center
    {
        float acc[64];
#pragma unroll
        for (int i = 0; i < 64; ++i) acc[i] = b3[cb * 64 + i];
#pragma unroll 2
        for (int j = 0; j < 64; ++j) {
            float a = h2T[j * 64 + r];
            const float* wrow = w3T + j * 128 + cb * 64;
#pragma unroll
            for (int i = 0; i < 64; ++i) acc[i] = fmaf(a, wrow[i], acc[i]);
        }
#pragma unroll
        for (int i = 0; i < 64; ++i) {
            float v = fmaxf(acc[i], 0.0f);
            v = fmaxf(v, __shfl_xor(v, 1));
            v = fmaxf(v, __shfl_xor(v, 2));
            v = fmaxf(v, __shfl_xor(v, 4));
            v = fmaxf(v, __shfl_xor(v, 8));
            v = fmaxf(v, __shfl_xor(v, 16));
            acc[i] = v;
        }
        if ((l & 31) == 0) {
            int sA = s0 + (l >> 5);
            float* op = out1 + ((size_t)b * 128 + cb * 64) * SS + sA;
#pragma unroll
            for (int i = 0; i < 64; ++i) op[(size_t)i * SS] = acc[i];
        }
    }
}

extern "C" void kernel_launch(void* const* d_in, const int* in_sizes, int n_in,
                              void* d_out, int out_size, void* d_ws, size_t ws_size,
                              hipStream_t stream) {
    (void)in_sizes; (void)n_in; (void)out_size; (void)ws_size;
    const float* xyz = (const float*)d_in[0];
    // d_in[1] = features : unused by the reference
    const float* w1 = (const float*)d_in[2];
    const float* b1 = (const float*)d_in[3];
    const float* w2 = (const float*)d_in[4];
    const float* b2 = (const float*)d_in[5];
    const float* w3 = (const float*)d_in[6];
    const float* b3 = (const float*)d_in[7];
    float* out = (float*)d_out;

    // workspace layout
    float4* wsCtr = (float4*)d_ws;              // B*S float4      (256 KB)
    float4* wsSorted = wsCtr + BB * SS;         // B*N float4      (1 MB)
    float* w1T = (float*)(wsSorted + BB * NN);  // 192 f
    float* w2T = w1T + 192;                     // 4096 f
    float* w3T = w2T + 4096;                    // 8192 f

    prep_kernel<<<1, 256, 0, stream>>>(w1, w2, w3, w1T, w2T, w3T);
    fps_kernel<<<BB, 512, 0, stream>>>(xyz, wsSorted, wsCtr, out);
    bqmlp_kernel<<<BB * (SS / 2), 128, 0, stream>>>(xyz, wsCtr, w1T, b1, w2T, b2,
                                                    w3T, b3, out + BB * 3 * SS);
}